// Round 1
// baseline (932.316 us; speedup 1.0000x reference)
//
#include <hip/hip_runtime.h>
#include <hip/hip_bf16.h>
#include <stdint.h>

#define D_MODEL 1024
#define NH 16
#define HD 64
#define BATCH 2
#define SEQ 2048
#define TOK (BATCH*SEQ)   // 4096 tokens

typedef __attribute__((ext_vector_type(8))) short short8;
typedef __attribute__((ext_vector_type(4))) float floatx4;

__device__ __forceinline__ unsigned short f2bf(float f) {
    union { float f; unsigned u; } v; v.f = f;
    unsigned r = v.u + 0x7fffu + ((v.u >> 16) & 1u);   // RNE
    return (unsigned short)(r >> 16);
}

// ---------------------------------------------------------------- convert
// ws bf16 layout (elements): Xb[4M] | Wq[1M] | Wk[1M] | Wv[1M] | Wo[1M]
__global__ __launch_bounds__(256)
void convert_all(const float* __restrict__ X,
                 const float* __restrict__ Wq, const float* __restrict__ Wk,
                 const float* __restrict__ Wv, const float* __restrict__ Wo,
                 unsigned short* __restrict__ dst) {
    size_t i = ((size_t)blockIdx.x * 256 + threadIdx.x) * 4;
    const float* src; size_t off;
    if (i < 4194304u)      { src = X;  off = 0; }
    else if (i < 5242880u) { src = Wq; off = 4194304u; }
    else if (i < 6291456u) { src = Wk; off = 5242880u; }
    else if (i < 7340032u) { src = Wv; off = 6291456u; }
    else                   { src = Wo; off = 7340032u; }
    float4 v = *(const float4*)(src + (i - off));
    ushort4 o;
    o.x = f2bf(v.x); o.y = f2bf(v.y); o.z = f2bf(v.z); o.w = f2bf(v.w);
    *(ushort4*)(dst + i) = o;
}

// ---------------------------------------------------------------- QKV GEMM
// C[m,n] = sum_k X[m,k]*W[n,k] + b[n];  M=4096, N=3072 (Q|K|V), K=1024
// Q,K -> [B][NH][S][HD] bf16 ; V -> transposed [B][NH][HD][S] bf16
__global__ __launch_bounds__(256)
void gemm_qkv(const unsigned short* __restrict__ Xb,
              const unsigned short* __restrict__ Wqb,
              const unsigned short* __restrict__ Wkb,
              const unsigned short* __restrict__ Wvb,
              const float* __restrict__ bq, const float* __restrict__ bk,
              const float* __restrict__ bv,
              unsigned short* __restrict__ Q,
              unsigned short* __restrict__ Kt,
              unsigned short* __restrict__ Vt) {
    const int m0 = blockIdx.x * 128;
    const int n0 = blockIdx.y * 128;          // 0..3071
    const int mat = n0 >> 10;                 // 0=Q 1=K 2=V
    const int nl0 = n0 & 1023;
    const unsigned short* Wp = (mat == 0) ? Wqb : (mat == 1) ? Wkb : Wvb;
    const float* bp = (mat == 0) ? bq : (mat == 1) ? bk : bv;

    __shared__ __attribute__((aligned(16))) unsigned short Al[128 * 40]; // pad 32->40
    __shared__ __attribute__((aligned(16))) unsigned short Bl[128 * 40];

    const int tid = threadIdx.x;
    const int wave = tid >> 6, lane = tid & 63;
    const int wm = (wave >> 1) * 64, wn = (wave & 1) * 64;
    const int lr = lane & 15, lk = lane >> 4;

    floatx4 acc[4][4];
#pragma unroll
    for (int i = 0; i < 4; i++)
#pragma unroll
        for (int j = 0; j < 4; j++) acc[i][j] = (floatx4){0.f, 0.f, 0.f, 0.f};

    for (int k0 = 0; k0 < 1024; k0 += 32) {
        __syncthreads();
#pragma unroll
        for (int c = tid; c < 512; c += 256) {
            int row = c >> 2, col = (c & 3) << 3;
            *(int4*)(Al + row * 40 + col) =
                *(const int4*)(Xb + (size_t)(m0 + row) * 1024 + k0 + col);
        }
#pragma unroll
        for (int c = tid; c < 512; c += 256) {
            int row = c >> 2, col = (c & 3) << 3;
            *(int4*)(Bl + row * 40 + col) =
                *(const int4*)(Wp + (size_t)(nl0 + row) * 1024 + k0 + col);
        }
        __syncthreads();
        short8 af[4], bf[4];
#pragma unroll
        for (int i = 0; i < 4; i++)
            af[i] = *(const short8*)(Al + (wm + i * 16 + lr) * 40 + lk * 8);
#pragma unroll
        for (int j = 0; j < 4; j++)
            bf[j] = *(const short8*)(Bl + (wn + j * 16 + lr) * 40 + lk * 8);
#pragma unroll
        for (int i = 0; i < 4; i++)
#pragma unroll
            for (int j = 0; j < 4; j++)
                acc[i][j] = __builtin_amdgcn_mfma_f32_16x16x32_bf16(af[i], bf[j], acc[i][j], 0, 0, 0);
    }

#pragma unroll
    for (int i = 0; i < 4; i++) {
#pragma unroll
        for (int j = 0; j < 4; j++) {
            int ncol = nl0 + wn + j * 16 + lr;      // 0..1023 in this matrix
            int h = ncol >> 6, d = ncol & 63;
            float bias = bp[ncol];
#pragma unroll
            for (int r = 0; r < 4; r++) {
                int m = m0 + wm + i * 16 + lk * 4 + r;
                int b = m >> 11, s = m & 2047;
                unsigned short v16 = f2bf(acc[i][j][r] + bias);
                if (mat == 2) {
                    Vt[((size_t)(b * NH + h) * HD + d) * SEQ + s] = v16;
                } else if (mat == 0) {
                    Q[((size_t)(b * NH + h) * SEQ + s) * HD + d] = v16;
                } else {
                    Kt[((size_t)(b * NH + h) * SEQ + s) * HD + d] = v16;
                }
            }
        }
    }
}

// ---------------------------------------------------------------- attention
// per block: one (b,h) head, 64 q-rows. Two passes over k-tiles.
__global__ __launch_bounds__(256)
void attn_fused(const unsigned short* __restrict__ Q,
                const unsigned short* __restrict__ K,
                const unsigned short* __restrict__ Vt,
                float* __restrict__ attn,           // [B][NH][S][S]
                unsigned short* __restrict__ Ab) {  // [TOK][1024] bf16
    const int qt = blockIdx.x;      // 0..31
    const int h = blockIdx.y, b = blockIdx.z;
    const size_t headQK = (size_t)(b * NH + h) * SEQ * HD;
    const size_t headV  = (size_t)(b * NH + h) * HD * SEQ;
    const unsigned short* Qh = Q + headQK;
    const unsigned short* Kh = K + headQK;
    const unsigned short* Vh = Vt + headV;
    float* attnRow = attn + (size_t)(b * NH + h) * SEQ * SEQ;

    __shared__ __attribute__((aligned(16))) unsigned short Ql[64 * 72]; // pad 64->72
    __shared__ __attribute__((aligned(16))) unsigned short Kl[64 * 72];
    __shared__ __attribute__((aligned(16))) unsigned short Vl[64 * 72];
    __shared__ __attribute__((aligned(16))) unsigned short Pl[64 * 72];

    const int tid = threadIdx.x;
    const int wave = tid >> 6, lane = tid & 63;
    const int lr = lane & 15, lk = lane >> 4;
    const int q0 = qt * 64;
    const int qrow_l = wave * 16 + lk * 4;     // + r

    // stage Q tile (contiguous 64x64 bf16)
    for (int c = tid; c < 512; c += 256) {
        int row = c >> 3, col = (c & 7) << 3;
        *(int4*)(Ql + row * 72 + col) = *(const int4*)(Qh + (size_t)(q0 + row) * HD + col);
    }

    const float NEG = -3.0e38f;
    float m_r[4] = {NEG, NEG, NEG, NEG};
    float l_r[4] = {0.f, 0.f, 0.f, 0.f};
    floatx4 oacc[4];
#pragma unroll
    for (int n = 0; n < 4; n++) oacc[n] = (floatx4){0.f, 0.f, 0.f, 0.f};

    // -------- pass A: raw scores + online (m,l)
    for (int kt = 0; kt <= qt; ++kt) {
        __syncthreads();
        for (int c = tid; c < 512; c += 256) {
            int row = c >> 3, col = (c & 7) << 3;
            *(int4*)(Kl + row * 72 + col) =
                *(const int4*)(Kh + (size_t)(kt * 64 + row) * HD + col);
        }
        __syncthreads();
        short8 a0 = *(const short8*)(Ql + (wave * 16 + lr) * 72 + lk * 8);
        short8 a1 = *(const short8*)(Ql + (wave * 16 + lr) * 72 + 32 + lk * 8);
        floatx4 sf[4];
#pragma unroll
        for (int n = 0; n < 4; ++n) {
            short8 b0 = *(const short8*)(Kl + (n * 16 + lr) * 72 + lk * 8);
            short8 b1 = *(const short8*)(Kl + (n * 16 + lr) * 72 + 32 + lk * 8);
            floatx4 z = (floatx4){0.f, 0.f, 0.f, 0.f};
            z = __builtin_amdgcn_mfma_f32_16x16x32_bf16(a0, b0, z, 0, 0, 0);
            z = __builtin_amdgcn_mfma_f32_16x16x32_bf16(a1, b1, z, 0, 0, 0);
            sf[n] = z;
        }
#pragma unroll
        for (int n = 0; n < 4; ++n)
#pragma unroll
            for (int r = 0; r < 4; ++r) {
                float s = sf[n][r] * 0.125f;
                int kg = kt * 64 + n * 16 + lr;
                int qg = q0 + qrow_l + r;
                if (kt == qt && kg > qg) s = NEG;
                sf[n][r] = s;
                attnRow[(size_t)qg * SEQ + kg] = s;   // raw score
            }
#pragma unroll
        for (int r = 0; r < 4; ++r) {
            float v = fmaxf(fmaxf(sf[0][r], sf[1][r]), fmaxf(sf[2][r], sf[3][r]));
            v = fmaxf(v, __shfl_xor(v, 1));
            v = fmaxf(v, __shfl_xor(v, 2));
            v = fmaxf(v, __shfl_xor(v, 4));
            v = fmaxf(v, __shfl_xor(v, 8));
            float mnew = fmaxf(m_r[r], v);
            float alpha = __expf(m_r[r] - mnew);
            float rs = __expf(sf[0][r] - mnew) + __expf(sf[1][r] - mnew) +
                       __expf(sf[2][r] - mnew) + __expf(sf[3][r] - mnew);
            rs += __shfl_xor(rs, 1); rs += __shfl_xor(rs, 2);
            rs += __shfl_xor(rs, 4); rs += __shfl_xor(rs, 8);
            l_r[r] = l_r[r] * alpha + rs;
            m_r[r] = mnew;
        }
    }

    float rl[4];
#pragma unroll
    for (int r = 0; r < 4; ++r) rl[r] = 1.0f / l_r[r];

    // -------- pass B: normalize attn, write final, O += P*V
    for (int kt = 0; kt <= qt; ++kt) {
        __syncthreads();
        for (int c = tid; c < 512; c += 256) {
            int row = c >> 3, col = (c & 7) << 3;
            *(int4*)(Vl + row * 72 + col) =
                *(const int4*)(Vh + (size_t)row * SEQ + kt * 64 + col);
        }
#pragma unroll
        for (int n = 0; n < 4; ++n)
#pragma unroll
            for (int r = 0; r < 4; ++r) {
                int kg = kt * 64 + n * 16 + lr;
                int qg = q0 + qrow_l + r;
                size_t idx = (size_t)qg * SEQ + kg;
                float p = __expf(attnRow[idx] - m_r[r]) * rl[r];
                attnRow[idx] = p;
                Pl[(qrow_l + r) * 72 + n * 16 + lr] = f2bf(p);
            }
        __syncthreads();
        short8 p0 = *(const short8*)(Pl + (wave * 16 + lr) * 72 + lk * 8);
        short8 p1 = *(const short8*)(Pl + (wave * 16 + lr) * 72 + 32 + lk * 8);
#pragma unroll
        for (int n = 0; n < 4; ++n) {
            short8 v0 = *(const short8*)(Vl + (n * 16 + lr) * 72 + lk * 8);
            short8 v1 = *(const short8*)(Vl + (n * 16 + lr) * 72 + 32 + lk * 8);
            oacc[n] = __builtin_amdgcn_mfma_f32_16x16x32_bf16(p0, v0, oacc[n], 0, 0, 0);
            oacc[n] = __builtin_amdgcn_mfma_f32_16x16x32_bf16(p1, v1, oacc[n], 0, 0, 0);
        }
    }

    // write O strip -> Ab [token][h*64+d] bf16
#pragma unroll
    for (int n = 0; n < 4; ++n)
#pragma unroll
        for (int r = 0; r < 4; ++r) {
            int sq = q0 + qrow_l + r;
            int d = n * 16 + lr;
            Ab[(size_t)(b * SEQ + sq) * D_MODEL + h * HD + d] = f2bf(oacc[n][r]);
        }

    // zero-fill causal upper region: rows q0..q0+63, cols (qt+1)*64 .. SEQ
    int c0 = (qt + 1) * 64;
    int zc = SEQ - c0;
    if (zc > 0) {
        float4 z4 = {0.f, 0.f, 0.f, 0.f};
        int per_row = zc >> 2;
        for (int row = 0; row < 64; ++row) {
            float4* dstp = (float4*)(attnRow + (size_t)(q0 + row) * SEQ + c0);
            for (int c = tid; c < per_row; c += 256) dstp[c] = z4;
        }
    }
}

// ---------------------------------------------------------------- out GEMM
// out[m,n] = sum_k Ab[m,k]*Wo[n,k] + bo[n];  M=4096, N=1024, K=1024, fp32 out
__global__ __launch_bounds__(256)
void gemm_out(const unsigned short* __restrict__ Ab,
              const unsigned short* __restrict__ Wob,
              const float* __restrict__ bo,
              float* __restrict__ out) {
    const int m0 = blockIdx.x * 128;
    const int n0 = blockIdx.y * 128;

    __shared__ __attribute__((aligned(16))) unsigned short Al[128 * 40];
    __shared__ __attribute__((aligned(16))) unsigned short Bl[128 * 40];

    const int tid = threadIdx.x;
    const int wave = tid >> 6, lane = tid & 63;
    const int wm = (wave >> 1) * 64, wn = (wave & 1) * 64;
    const int lr = lane & 15, lk = lane >> 4;

    floatx4 acc[4][4];
#pragma unroll
    for (int i = 0; i < 4; i++)
#pragma unroll
        for (int j = 0; j < 4; j++) acc[i][j] = (floatx4){0.f, 0.f, 0.f, 0.f};

    for (int k0 = 0; k0 < 1024; k0 += 32) {
        __syncthreads();
#pragma unroll
        for (int c = tid; c < 512; c += 256) {
            int row = c >> 2, col = (c & 3) << 3;
            *(int4*)(Al + row * 40 + col) =
                *(const int4*)(Ab + (size_t)(m0 + row) * 1024 + k0 + col);
        }
#pragma unroll
        for (int c = tid; c < 512; c += 256) {
            int row = c >> 2, col = (c & 3) << 3;
            *(int4*)(Bl + row * 40 + col) =
                *(const int4*)(Wob + (size_t)(n0 + row) * 1024 + k0 + col);
        }
        __syncthreads();
        short8 af[4], bf[4];
#pragma unroll
        for (int i = 0; i < 4; i++)
            af[i] = *(const short8*)(Al + (wm + i * 16 + lr) * 40 + lk * 8);
#pragma unroll
        for (int j = 0; j < 4; j++)
            bf[j] = *(const short8*)(Bl + (wn + j * 16 + lr) * 40 + lk * 8);
#pragma unroll
        for (int i = 0; i < 4; i++)
#pragma unroll
            for (int j = 0; j < 4; j++)
                acc[i][j] = __builtin_amdgcn_mfma_f32_16x16x32_bf16(af[i], bf[j], acc[i][j], 0, 0, 0);
    }

#pragma unroll
    for (int i = 0; i < 4; i++)
#pragma unroll
        for (int j = 0; j < 4; j++) {
            int n = n0 + wn + j * 16 + lr;
            float bias = bo[n];
#pragma unroll
            for (int r = 0; r < 4; r++) {
                int m = m0 + wm + i * 16 + lk * 4 + r;
                out[(size_t)m * 1024 + n] = acc[i][j][r] + bias;
            }
        }
}

// ---------------------------------------------------------------- launch
extern "C" void kernel_launch(void* const* d_in, const int* in_sizes, int n_in,
                              void* d_out, int out_size, void* d_ws, size_t ws_size,
                              hipStream_t stream) {
    (void)in_sizes; (void)n_in; (void)out_size; (void)ws_size;
    const float* X  = (const float*)d_in[0];
    const float* Wq = (const float*)d_in[1];
    const float* bq = (const float*)d_in[2];
    const float* Wk = (const float*)d_in[3];
    const float* bk = (const float*)d_in[4];
    const float* Wv = (const float*)d_in[5];
    const float* bv = (const float*)d_in[6];
    const float* Wo = (const float*)d_in[7];
    const float* bo = (const float*)d_in[8];

    float* out  = (float*)d_out;
    float* attn = out + (size_t)TOK * D_MODEL;   // output 1 starts after `out`

    unsigned short* wsb = (unsigned short*)d_ws;
    unsigned short* Xb  = wsb;                   // 4M elems
    unsigned short* Wqb = wsb + 4194304u;
    unsigned short* Wkb = wsb + 5242880u;
    unsigned short* Wvb = wsb + 6291456u;
    unsigned short* Wob = wsb + 7340032u;
    unsigned short* Qb  = wsb + 8388608u;        // [B][NH][S][HD]
    unsigned short* Kb  = wsb + 12582912u;
    unsigned short* Vtb = wsb + 16777216u;       // [B][NH][HD][S]
    unsigned short* Abf = wsb + 20971520u;       // [TOK][1024]  (ends at 48 MiB)

    convert_all<<<8192, 256, 0, stream>>>(X, Wq, Wk, Wv, Wo, wsb);
    gemm_qkv<<<dim3(32, 24), 256, 0, stream>>>(Xb, Wqb, Wkb, Wvb, bq, bk, bv, Qb, Kb, Vtb);
    attn_fused<<<dim3(32, NH, BATCH), 256, 0, stream>>>(Qb, Kb, Vtb, attn, Abf);
    gemm_out<<<dim3(32, 8), 256, 0, stream>>>(Abf, Wob, bo, out);
}

// Round 2
// 779.225 us; speedup vs baseline: 1.1965x; 1.1965x over previous
//
#include <hip/hip_runtime.h>
#include <hip/hip_bf16.h>
#include <stdint.h>

#define D_MODEL 1024
#define NH 16
#define HD 64
#define BATCH 2
#define SEQ 2048
#define TOK (BATCH*SEQ)   // 4096 tokens

typedef __attribute__((ext_vector_type(8))) short short8;
typedef __attribute__((ext_vector_type(4))) float floatx4;

__device__ __forceinline__ unsigned short f2bf(float f) {
    union { float f; unsigned u; } v; v.f = f;
    unsigned r = v.u + 0x7fffu + ((v.u >> 16) & 1u);   // RNE
    return (unsigned short)(r >> 16);
}

// ---------------------------------------------------------------- convert
// ws bf16 layout (elements): Xb[4M] | Wq[1M] | Wk[1M] | Wv[1M] | Wo[1M]
__global__ __launch_bounds__(256)
void convert_all(const float* __restrict__ X,
                 const float* __restrict__ Wq, const float* __restrict__ Wk,
                 const float* __restrict__ Wv, const float* __restrict__ Wo,
                 unsigned short* __restrict__ dst) {
    size_t i = ((size_t)blockIdx.x * 256 + threadIdx.x) * 4;
    const float* src; size_t off;
    if (i < 4194304u)      { src = X;  off = 0; }
    else if (i < 5242880u) { src = Wq; off = 4194304u; }
    else if (i < 6291456u) { src = Wk; off = 5242880u; }
    else if (i < 7340032u) { src = Wv; off = 6291456u; }
    else                   { src = Wo; off = 7340032u; }
    float4 v = *(const float4*)(src + (i - off));
    ushort4 o;
    o.x = f2bf(v.x); o.y = f2bf(v.y); o.z = f2bf(v.z); o.w = f2bf(v.w);
    *(ushort4*)(dst + i) = o;
}

// ---------------------------------------------------------------- QKV GEMM
// C[m,n] = sum_k X[m,k]*W[n,k] + b[n];  M=4096, N=3072 (Q|K|V), K=1024
// Q,K,V all -> [B*NH][S][HD] bf16 (coalesced stores; V transposed later)
__global__ __launch_bounds__(256)
void gemm_qkv(const unsigned short* __restrict__ Xb,
              const unsigned short* __restrict__ Wqb,
              const unsigned short* __restrict__ Wkb,
              const unsigned short* __restrict__ Wvb,
              const float* __restrict__ bq, const float* __restrict__ bk,
              const float* __restrict__ bv,
              unsigned short* __restrict__ Q,
              unsigned short* __restrict__ Kb,
              unsigned short* __restrict__ Vr) {
    const int m0 = blockIdx.x * 128;
    const int n0 = blockIdx.y * 128;          // 0..3071
    const int mat = n0 >> 10;                 // 0=Q 1=K 2=V
    const int nl0 = n0 & 1023;
    const unsigned short* Wp = (mat == 0) ? Wqb : (mat == 1) ? Wkb : Wvb;
    const float* bp = (mat == 0) ? bq : (mat == 1) ? bk : bv;
    unsigned short* Dst = (mat == 0) ? Q : (mat == 1) ? Kb : Vr;

    __shared__ __attribute__((aligned(16))) unsigned short Al[128 * 40]; // pad 32->40
    __shared__ __attribute__((aligned(16))) unsigned short Bl[128 * 40];

    const int tid = threadIdx.x;
    const int wave = tid >> 6, lane = tid & 63;
    const int wm = (wave >> 1) * 64, wn = (wave & 1) * 64;
    const int lr = lane & 15, lk = lane >> 4;

    floatx4 acc[4][4];
#pragma unroll
    for (int i = 0; i < 4; i++)
#pragma unroll
        for (int j = 0; j < 4; j++) acc[i][j] = (floatx4){0.f, 0.f, 0.f, 0.f};

    for (int k0 = 0; k0 < 1024; k0 += 32) {
        __syncthreads();
#pragma unroll
        for (int c = tid; c < 512; c += 256) {
            int row = c >> 2, col = (c & 3) << 3;
            *(int4*)(Al + row * 40 + col) =
                *(const int4*)(Xb + (size_t)(m0 + row) * 1024 + k0 + col);
        }
#pragma unroll
        for (int c = tid; c < 512; c += 256) {
            int row = c >> 2, col = (c & 3) << 3;
            *(int4*)(Bl + row * 40 + col) =
                *(const int4*)(Wp + (size_t)(nl0 + row) * 1024 + k0 + col);
        }
        __syncthreads();
        short8 af[4], bf[4];
#pragma unroll
        for (int i = 0; i < 4; i++)
            af[i] = *(const short8*)(Al + (wm + i * 16 + lr) * 40 + lk * 8);
#pragma unroll
        for (int j = 0; j < 4; j++)
            bf[j] = *(const short8*)(Bl + (wn + j * 16 + lr) * 40 + lk * 8);
#pragma unroll
        for (int i = 0; i < 4; i++)
#pragma unroll
            for (int j = 0; j < 4; j++)
                acc[i][j] = __builtin_amdgcn_mfma_f32_16x16x32_bf16(af[i], bf[j], acc[i][j], 0, 0, 0);
    }

#pragma unroll
    for (int i = 0; i < 4; i++) {
#pragma unroll
        for (int j = 0; j < 4; j++) {
            int ncol = nl0 + wn + j * 16 + lr;      // 0..1023 in this matrix
            int h = ncol >> 6, d = ncol & 63;
            float bias = bp[ncol];
#pragma unroll
            for (int r = 0; r < 4; r++) {
                int m = m0 + wm + i * 16 + lk * 4 + r;
                int b = m >> 11, s = m & 2047;
                Dst[((size_t)(b * NH + h) * SEQ + s) * HD + d] = f2bf(acc[i][j][r] + bias);
            }
        }
    }
}

// ---------------------------------------------------------------- V transpose
// Vr [B*NH][S][HD] -> Vt [B*NH][HD][S], 64x64 LDS tiles
__global__ __launch_bounds__(256)
void transpose_v(const unsigned short* __restrict__ Vr,
                 unsigned short* __restrict__ Vt) {
    const int st = blockIdx.x;        // seq tile 0..31
    const int bh = blockIdx.y;        // 0..31
    const int s0 = st * 64;
    const unsigned short* src = Vr + (size_t)bh * SEQ * HD;
    unsigned short* dst = Vt + (size_t)bh * HD * SEQ;

    __shared__ __attribute__((aligned(16))) unsigned short Tl[64 * 72];
    const int tid = threadIdx.x;

#pragma unroll
    for (int c = tid; c < 512; c += 256) {
        int row = c >> 3, col = (c & 7) << 3;
        *(int4*)(Tl + row * 72 + col) =
            *(const int4*)(src + (size_t)(s0 + row) * HD + col);
    }
    __syncthreads();
#pragma unroll
    for (int c = tid; c < 512; c += 256) {
        int d = c >> 3, sc = (c & 7) << 3;
        short8 v;
#pragma unroll
        for (int j = 0; j < 8; ++j) v[j] = (short)Tl[(sc + j) * 72 + d];
        *(short8*)(dst + (size_t)d * SEQ + s0 + sc) = v;
    }
}

// ---------------------------------------------------------------- attention
// per block: one (b,h) head, 64 q-rows. Pass A: online (m,l) only (no HBM
// writes). Pass B: recompute QK^T, write final p once, PV via MFMA.
__global__ __launch_bounds__(256)
void attn_fused(const unsigned short* __restrict__ Q,
                const unsigned short* __restrict__ K,
                const unsigned short* __restrict__ Vt,
                float* __restrict__ attn,           // [B][NH][S][S]
                unsigned short* __restrict__ Ab) {  // [TOK][1024] bf16
    const int qt = 31 - blockIdx.x;   // heavy blocks first
    const int h = blockIdx.y, b = blockIdx.z;
    const size_t headQK = (size_t)(b * NH + h) * SEQ * HD;
    const size_t headV  = (size_t)(b * NH + h) * HD * SEQ;
    const unsigned short* Qh = Q + headQK;
    const unsigned short* Kh = K + headQK;
    const unsigned short* Vh = Vt + headV;
    float* attnRow = attn + (size_t)(b * NH + h) * SEQ * SEQ;

    __shared__ __attribute__((aligned(16))) unsigned short Ql[64 * 72]; // pad 64->72
    __shared__ __attribute__((aligned(16))) unsigned short Kl[64 * 72];
    __shared__ __attribute__((aligned(16))) unsigned short Vl[64 * 72];
    __shared__ __attribute__((aligned(16))) unsigned short Pl[64 * 72];

    const int tid = threadIdx.x;
    const int wave = tid >> 6, lane = tid & 63;
    const int lr = lane & 15, lk = lane >> 4;
    const int q0 = qt * 64;
    const int qrow_l = wave * 16 + lk * 4;     // + r

    // stage Q tile (contiguous 64x64 bf16)
    for (int c = tid; c < 512; c += 256) {
        int row = c >> 3, col = (c & 7) << 3;
        *(int4*)(Ql + row * 72 + col) = *(const int4*)(Qh + (size_t)(q0 + row) * HD + col);
    }
    __syncthreads();
    const short8 a0 = *(const short8*)(Ql + (wave * 16 + lr) * 72 + lk * 8);
    const short8 a1 = *(const short8*)(Ql + (wave * 16 + lr) * 72 + 32 + lk * 8);

    const float NEG = -3.0e38f;
    float m_r[4] = {NEG, NEG, NEG, NEG};
    float l_r[4] = {0.f, 0.f, 0.f, 0.f};
    floatx4 oacc[4];
#pragma unroll
    for (int n = 0; n < 4; n++) oacc[n] = (floatx4){0.f, 0.f, 0.f, 0.f};

    // -------- pass A: online (m,l), no global writes
    for (int kt = 0; kt <= qt; ++kt) {
        __syncthreads();
        for (int c = tid; c < 512; c += 256) {
            int row = c >> 3, col = (c & 7) << 3;
            *(int4*)(Kl + row * 72 + col) =
                *(const int4*)(Kh + (size_t)(kt * 64 + row) * HD + col);
        }
        __syncthreads();
        floatx4 sf[4];
#pragma unroll
        for (int n = 0; n < 4; ++n) {
            short8 b0 = *(const short8*)(Kl + (n * 16 + lr) * 72 + lk * 8);
            short8 b1 = *(const short8*)(Kl + (n * 16 + lr) * 72 + 32 + lk * 8);
            floatx4 z = (floatx4){0.f, 0.f, 0.f, 0.f};
            z = __builtin_amdgcn_mfma_f32_16x16x32_bf16(a0, b0, z, 0, 0, 0);
            z = __builtin_amdgcn_mfma_f32_16x16x32_bf16(a1, b1, z, 0, 0, 0);
            sf[n] = z;
        }
#pragma unroll
        for (int n = 0; n < 4; ++n)
#pragma unroll
            for (int r = 0; r < 4; ++r) {
                float s = sf[n][r] * 0.125f;
                int kg = kt * 64 + n * 16 + lr;
                int qg = q0 + qrow_l + r;
                if (kt == qt && kg > qg) s = NEG;
                sf[n][r] = s;
            }
#pragma unroll
        for (int r = 0; r < 4; ++r) {
            float v = fmaxf(fmaxf(sf[0][r], sf[1][r]), fmaxf(sf[2][r], sf[3][r]));
            v = fmaxf(v, __shfl_xor(v, 1));
            v = fmaxf(v, __shfl_xor(v, 2));
            v = fmaxf(v, __shfl_xor(v, 4));
            v = fmaxf(v, __shfl_xor(v, 8));
            float mnew = fmaxf(m_r[r], v);
            float alpha = __expf(m_r[r] - mnew);
            float rs = __expf(sf[0][r] - mnew) + __expf(sf[1][r] - mnew) +
                       __expf(sf[2][r] - mnew) + __expf(sf[3][r] - mnew);
            rs += __shfl_xor(rs, 1); rs += __shfl_xor(rs, 2);
            rs += __shfl_xor(rs, 4); rs += __shfl_xor(rs, 8);
            l_r[r] = l_r[r] * alpha + rs;
            m_r[r] = mnew;
        }
    }

    float rl[4];
#pragma unroll
    for (int r = 0; r < 4; ++r) rl[r] = 1.0f / l_r[r];

    // -------- pass B: recompute scores, write final p, O += P*V
    for (int kt = 0; kt <= qt; ++kt) {
        __syncthreads();
        for (int c = tid; c < 512; c += 256) {
            int row = c >> 3, col = (c & 7) << 3;
            *(int4*)(Kl + row * 72 + col) =
                *(const int4*)(Kh + (size_t)(kt * 64 + row) * HD + col);
            *(int4*)(Vl + row * 72 + col) =
                *(const int4*)(Vh + (size_t)row * SEQ + kt * 64 + col);
        }
        __syncthreads();
#pragma unroll
        for (int n = 0; n < 4; ++n) {
            short8 b0 = *(const short8*)(Kl + (n * 16 + lr) * 72 + lk * 8);
            short8 b1 = *(const short8*)(Kl + (n * 16 + lr) * 72 + 32 + lk * 8);
            floatx4 z = (floatx4){0.f, 0.f, 0.f, 0.f};
            z = __builtin_amdgcn_mfma_f32_16x16x32_bf16(a0, b0, z, 0, 0, 0);
            z = __builtin_amdgcn_mfma_f32_16x16x32_bf16(a1, b1, z, 0, 0, 0);
#pragma unroll
            for (int r = 0; r < 4; ++r) {
                float s = z[r] * 0.125f;
                int kg = kt * 64 + n * 16 + lr;
                int qg = q0 + qrow_l + r;
                if (kt == qt && kg > qg) s = NEG;
                float p = __expf(s - m_r[r]) * rl[r];
                attnRow[(size_t)qg * SEQ + kg] = p;
                Pl[(qrow_l + r) * 72 + n * 16 + lr] = f2bf(p);
            }
        }
        __syncthreads();
        short8 p0 = *(const short8*)(Pl + (wave * 16 + lr) * 72 + lk * 8);
        short8 p1 = *(const short8*)(Pl + (wave * 16 + lr) * 72 + 32 + lk * 8);
#pragma unroll
        for (int n = 0; n < 4; ++n) {
            short8 v0 = *(const short8*)(Vl + (n * 16 + lr) * 72 + lk * 8);
            short8 v1 = *(const short8*)(Vl + (n * 16 + lr) * 72 + 32 + lk * 8);
            oacc[n] = __builtin_amdgcn_mfma_f32_16x16x32_bf16(p0, v0, oacc[n], 0, 0, 0);
            oacc[n] = __builtin_amdgcn_mfma_f32_16x16x32_bf16(p1, v1, oacc[n], 0, 0, 0);
        }
    }

    // write O strip -> Ab [token][h*64+d] bf16
#pragma unroll
    for (int n = 0; n < 4; ++n)
#pragma unroll
        for (int r = 0; r < 4; ++r) {
            int sq = q0 + qrow_l + r;
            int d = n * 16 + lr;
            Ab[(size_t)(b * SEQ + sq) * D_MODEL + h * HD + d] = f2bf(oacc[n][r]);
        }

    // zero-fill causal upper region: rows q0..q0+63, cols (qt+1)*64 .. SEQ
    int c0 = (qt + 1) * 64;
    int zc = SEQ - c0;
    if (zc > 0) {
        float4 z4 = {0.f, 0.f, 0.f, 0.f};
        int per_row = zc >> 2;
        for (int row = 0; row < 64; ++row) {
            float4* dstp = (float4*)(attnRow + (size_t)(q0 + row) * SEQ + c0);
            for (int c = tid; c < per_row; c += 256) dstp[c] = z4;
        }
    }
}

// ---------------------------------------------------------------- out GEMM
// out[m,n] = sum_k Ab[m,k]*Wo[n,k] + bo[n];  M=4096, N=1024, K=1024, fp32 out
__global__ __launch_bounds__(256)
void gemm_out(const unsigned short* __restrict__ Ab,
              const unsigned short* __restrict__ Wob,
              const float* __restrict__ bo,
              float* __restrict__ out) {
    const int m0 = blockIdx.x * 128;
    const int n0 = blockIdx.y * 128;

    __shared__ __attribute__((aligned(16))) unsigned short Al[128 * 40];
    __shared__ __attribute__((aligned(16))) unsigned short Bl[128 * 40];

    const int tid = threadIdx.x;
    const int wave = tid >> 6, lane = tid & 63;
    const int wm = (wave >> 1) * 64, wn = (wave & 1) * 64;
    const int lr = lane & 15, lk = lane >> 4;

    floatx4 acc[4][4];
#pragma unroll
    for (int i = 0; i < 4; i++)
#pragma unroll
        for (int j = 0; j < 4; j++) acc[i][j] = (floatx4){0.f, 0.f, 0.f, 0.f};

    for (int k0 = 0; k0 < 1024; k0 += 32) {
        __syncthreads();
#pragma unroll
        for (int c = tid; c < 512; c += 256) {
            int row = c >> 2, col = (c & 3) << 3;
            *(int4*)(Al + row * 40 + col) =
                *(const int4*)(Ab + (size_t)(m0 + row) * 1024 + k0 + col);
        }
#pragma unroll
        for (int c = tid; c < 512; c += 256) {
            int row = c >> 2, col = (c & 3) << 3;
            *(int4*)(Bl + row * 40 + col) =
                *(const int4*)(Wob + (size_t)(n0 + row) * 1024 + k0 + col);
        }
        __syncthreads();
        short8 af[4], bf[4];
#pragma unroll
        for (int i = 0; i < 4; i++)
            af[i] = *(const short8*)(Al + (wm + i * 16 + lr) * 40 + lk * 8);
#pragma unroll
        for (int j = 0; j < 4; j++)
            bf[j] = *(const short8*)(Bl + (wn + j * 16 + lr) * 40 + lk * 8);
#pragma unroll
        for (int i = 0; i < 4; i++)
#pragma unroll
            for (int j = 0; j < 4; j++)
                acc[i][j] = __builtin_amdgcn_mfma_f32_16x16x32_bf16(af[i], bf[j], acc[i][j], 0, 0, 0);
    }

#pragma unroll
    for (int i = 0; i < 4; i++)
#pragma unroll
        for (int j = 0; j < 4; j++) {
            int n = n0 + wn + j * 16 + lr;
            float bias = bo[n];
#pragma unroll
            for (int r = 0; r < 4; r++) {
                int m = m0 + wm + i * 16 + lk * 4 + r;
                out[(size_t)m * 1024 + n] = acc[i][j][r] + bias;
            }
        }
}

// ---------------------------------------------------------------- launch
extern "C" void kernel_launch(void* const* d_in, const int* in_sizes, int n_in,
                              void* d_out, int out_size, void* d_ws, size_t ws_size,
                              hipStream_t stream) {
    (void)in_sizes; (void)n_in; (void)out_size; (void)ws_size;
    const float* X  = (const float*)d_in[0];
    const float* Wq = (const float*)d_in[1];
    const float* bq = (const float*)d_in[2];
    const float* Wk = (const float*)d_in[3];
    const float* bk = (const float*)d_in[4];
    const float* Wv = (const float*)d_in[5];
    const float* bv = (const float*)d_in[6];
    const float* Wo = (const float*)d_in[7];
    const float* bo = (const float*)d_in[8];

    float* out  = (float*)d_out;
    float* attn = out + (size_t)TOK * D_MODEL;   // output 1 starts after `out`

    unsigned short* wsb = (unsigned short*)d_ws;
    unsigned short* Xb  = wsb;                   // 4M elems; reused as Vt after gemm_qkv
    unsigned short* Wqb = wsb + 4194304u;
    unsigned short* Wkb = wsb + 5242880u;
    unsigned short* Wvb = wsb + 6291456u;
    unsigned short* Wob = wsb + 7340032u;
    unsigned short* Qb  = wsb + 8388608u;        // [B*NH][S][HD]
    unsigned short* Kb  = wsb + 12582912u;       // [B*NH][S][HD]
    unsigned short* Vrb = wsb + 16777216u;       // [B*NH][S][HD]
    unsigned short* Abf = wsb + 20971520u;       // [TOK][1024]  (ends at 48 MiB)
    unsigned short* Vtb = Xb;                    // [B*NH][HD][S] (Xb dead after gemm_qkv)

    convert_all<<<8192, 256, 0, stream>>>(X, Wq, Wk, Wv, Wo, wsb);
    gemm_qkv<<<dim3(32, 24), 256, 0, stream>>>(Xb, Wqb, Wkb, Wvb, bq, bk, bv, Qb, Kb, Vrb);
    transpose_v<<<dim3(32, 32), 256, 0, stream>>>(Vrb, Vtb);
    attn_fused<<<dim3(32, NH, BATCH), 256, 0, stream>>>(Qb, Kb, Vtb, attn, Abf);
    gemm_out<<<dim3(32, 8), 256, 0, stream>>>(Abf, Wob, bo, out);
}